// Round 1
// baseline (71.610 us; speedup 1.0000x reference)
//
#include <hip/hip_runtime.h>
#include <math.h>

#define V 50257
#define H 1024
#define E 512
#define L 128
#define HE 1536            // H + E
#define NBLK5 2048         // blocks for vocab matvec -> 8192 waves

// ws layout (floats)
#define WS_DECRAW 0        // 1536: [embed(512) | attn_out(1024)]
#define WS_DECIN  1536     // 1024: relu(a2d)
#define WS_HNEW   2560     // 1024: aligned copy of h_new
#define WS_ALOGIT 3584     // 128 : raw attention logits
#define WS_PAIRS  3712     // 2*NBLK5: (max, sumexp) per k_vocab block

__device__ __forceinline__ float wave_reduce_sum(float v) {
    #pragma unroll
    for (int off = 32; off > 0; off >>= 1) v += __shfl_xor(v, off, 64);
    return v;
}

// ---------------- K1a: attention logits (16 blocks x 256) ----------------
__global__ void k_attn_logits(const int* __restrict__ tok_p,
                              const float* __restrict__ h0,
                              const float* __restrict__ emb,
                              const float* __restrict__ attn_W,
                              const float* __restrict__ attn_b,
                              float* __restrict__ ws) {
    __shared__ __align__(16) float s_in[HE];
    const int tid = threadIdx.x;
    const int tok = tok_p[0];
    for (int k = tid; k < HE; k += 256) {
        float v = (k < E) ? emb[(size_t)tok * E + k] : h0[k - E];
        s_in[k] = v;
        if (blockIdx.x == 0 && k < E) ws[WS_DECRAW + k] = v;  // embed slice of dec_in_raw
    }
    __syncthreads();
    const int lane = tid & 63;
    const int gw = (blockIdx.x << 2) + (tid >> 6);   // 0..63
    const float4* s4 = (const float4*)s_in;
    #pragma unroll
    for (int rr = 0; rr < 2; ++rr) {
        const int r = gw * 2 + rr;                   // 0..127
        const float4* w4 = (const float4*)(attn_W + (size_t)r * HE);
        float acc = 0.f;
        #pragma unroll
        for (int c = 0; c < 6; ++c) {
            float4 a = s4[lane + (c << 6)];
            float4 b = w4[lane + (c << 6)];
            acc = fmaf(a.x, b.x, acc); acc = fmaf(a.y, b.y, acc);
            acc = fmaf(a.z, b.z, acc); acc = fmaf(a.w, b.w, acc);
        }
        acc = wave_reduce_sum(acc);
        if (lane == 0) ws[WS_ALOGIT + r] = acc + attn_b[r];
    }
}

// ---------------- K1b: softmax + attn_out (4 blocks x 256) ----------------
__global__ void k_attn_out(const float* __restrict__ enc,
                           float* __restrict__ out_attnw,
                           float* __restrict__ ws) {
    __shared__ float s_l[L];
    __shared__ float s_wn[L];
    const int tid = threadIdx.x;
    if (tid < L) s_l[tid] = ws[WS_ALOGIT + tid];
    __syncthreads();
    if (tid < L) {
        float m = -1e30f;
        for (int l = 0; l < L; ++l) m = fmaxf(m, s_l[l]);
        float s = 0.f;
        for (int l = 0; l < L; ++l) s += expf(s_l[l] - m);
        float wn = expf(s_l[tid] - m) / s;
        s_wn[tid] = wn;
        if (blockIdx.x == 0) out_attnw[tid] = wn;
    }
    __syncthreads();
    const int j = blockIdx.x * 256 + tid;            // 0..1023
    float acc = 0.f;
    for (int l = 0; l < L; ++l) acc = fmaf(s_wn[l], enc[l * H + j], acc);
    ws[WS_DECRAW + E + j] = acc;
}

// ---------------- K2: dec_in = relu(dec_in_raw @ a2d_W.T + b) -------------
__global__ void k_a2d(const float* __restrict__ a2d_W,
                      const float* __restrict__ a2d_b,
                      float* __restrict__ ws) {
    const int lane = threadIdx.x & 63;
    const int r = (blockIdx.x << 2) + (threadIdx.x >> 6);  // 0..1023
    const float4* x4 = (const float4*)(ws + WS_DECRAW);
    const float4* w4 = (const float4*)(a2d_W + (size_t)r * HE);
    float acc = 0.f;
    #pragma unroll
    for (int c = 0; c < 6; ++c) {
        float4 a = x4[lane + (c << 6)];
        float4 b = w4[lane + (c << 6)];
        acc = fmaf(a.x, b.x, acc); acc = fmaf(a.y, b.y, acc);
        acc = fmaf(a.z, b.z, acc); acc = fmaf(a.w, b.w, acc);
    }
    acc = wave_reduce_sum(acc);
    if (lane == 0) ws[WS_DECIN + r] = fmaxf(acc + a2d_b[r], 0.f);
}

// ---------------- K3: gates + LSTM pointwise (wave per output j) ----------
__global__ void k_lstm(const float* __restrict__ h0,
                       const float* __restrict__ c0,
                       const float* __restrict__ W_ih,
                       const float* __restrict__ W_hh,
                       const float* __restrict__ b_ih,
                       const float* __restrict__ b_hh,
                       float* __restrict__ out_h,
                       float* __restrict__ out_c,
                       float* __restrict__ ws) {
    const int lane = threadIdx.x & 63;
    const int j = (blockIdx.x << 2) + (threadIdx.x >> 6);  // 0..1023
    const float4* x4 = (const float4*)(ws + WS_DECIN);
    const float4* h4 = (const float4*)h0;
    float4 xr[4], hr[4];
    #pragma unroll
    for (int k = 0; k < 4; ++k) {
        xr[k] = x4[lane + (k << 6)];
        hr[k] = h4[lane + (k << 6)];
    }
    float g[4];
    #pragma unroll
    for (int gi = 0; gi < 4; ++gi) {
        const size_t r = (size_t)gi * H + j;
        const float4* wi4 = (const float4*)(W_ih + r * H);
        const float4* wh4 = (const float4*)(W_hh + r * H);
        float acc = 0.f;
        #pragma unroll
        for (int k = 0; k < 4; ++k) {
            float4 a = wi4[lane + (k << 6)];
            acc = fmaf(xr[k].x, a.x, acc); acc = fmaf(xr[k].y, a.y, acc);
            acc = fmaf(xr[k].z, a.z, acc); acc = fmaf(xr[k].w, a.w, acc);
            float4 b = wh4[lane + (k << 6)];
            acc = fmaf(hr[k].x, b.x, acc); acc = fmaf(hr[k].y, b.y, acc);
            acc = fmaf(hr[k].z, b.z, acc); acc = fmaf(hr[k].w, b.w, acc);
        }
        g[gi] = wave_reduce_sum(acc);
    }
    if (lane == 0) {
        float gi_ = g[0] + b_ih[j]         + b_hh[j];
        float gf  = g[1] + b_ih[H + j]     + b_hh[H + j];
        float gg  = g[2] + b_ih[2 * H + j] + b_hh[2 * H + j];
        float go  = g[3] + b_ih[3 * H + j] + b_hh[3 * H + j];
        float si = 1.f / (1.f + expf(-gi_));
        float sf = 1.f / (1.f + expf(-gf));
        float so = 1.f / (1.f + expf(-go));
        float cn = sf * c0[j] + si * tanhf(gg);
        float hn = so * tanhf(cn);
        out_c[j] = cn;
        out_h[j] = hn;
        ws[WS_HNEW + j] = hn;   // 16B-aligned copy for k_vocab float4 reads
    }
}

// ---------------- K5: vocab matvec + per-block online softmax partials ----
__global__ void k_vocab(const float* __restrict__ out_W,
                        const float* __restrict__ out_b,
                        float* __restrict__ logits,
                        float* __restrict__ ws) {
    const int lane = threadIdx.x & 63;
    const int widx = threadIdx.x >> 6;
    const int gw = (blockIdx.x << 2) + widx;          // 0..8191
    const float4* h4 = (const float4*)(ws + WS_HNEW);
    float4 hr[4];
    #pragma unroll
    for (int k = 0; k < 4; ++k) hr[k] = h4[lane + (k << 6)];
    float m = -1e30f, s = 0.f;
    for (int v = gw; v < V; v += NBLK5 * 4) {
        const float4* w4 = (const float4*)(out_W + (size_t)v * H);
        float acc = 0.f;
        #pragma unroll
        for (int k = 0; k < 4; ++k) {
            float4 a = w4[lane + (k << 6)];
            acc = fmaf(hr[k].x, a.x, acc); acc = fmaf(hr[k].y, a.y, acc);
            acc = fmaf(hr[k].z, a.z, acc); acc = fmaf(hr[k].w, a.w, acc);
        }
        acc = wave_reduce_sum(acc);                   // uniform across lanes
        const float logit = acc + out_b[v];
        if (lane == 0) logits[v] = logit;
        const float mo = m;
        m = fmaxf(m, logit);
        s = s * __expf(mo - m) + __expf(logit - m);
    }
    __shared__ float sm[4], ss[4];
    if (lane == 0) { sm[widx] = m; ss[widx] = s; }
    __syncthreads();
    if (threadIdx.x == 0) {
        float M = sm[0], S = ss[0];
        #pragma unroll
        for (int i = 1; i < 4; ++i) {
            float Mn = fmaxf(M, sm[i]);
            S = S * __expf(M - Mn) + ss[i] * __expf(sm[i] - Mn);
            M = Mn;
        }
        ws[WS_PAIRS + 2 * blockIdx.x]     = M;
        ws[WS_PAIRS + 2 * blockIdx.x + 1] = S;
    }
}

// ---------------- K6: fold partials + finalize log-softmax ----------------
__global__ void k_final(float* __restrict__ logits,
                        const float* __restrict__ ws) {
    __shared__ float sm[256], ss[256];
    const int tid = threadIdx.x;
    float M = -1e30f, S = 0.f;
    for (int i = tid; i < NBLK5; i += 256) {
        float m2 = ws[WS_PAIRS + 2 * i], s2 = ws[WS_PAIRS + 2 * i + 1];
        float Mn = fmaxf(M, m2);
        S = S * __expf(M - Mn) + s2 * __expf(m2 - Mn);
        M = Mn;
    }
    sm[tid] = M; ss[tid] = S;
    __syncthreads();
    for (int off = 128; off > 0; off >>= 1) {
        if (tid < off) {
            float m2 = sm[tid + off], s2 = ss[tid + off];
            float Mn = fmaxf(sm[tid], m2);
            ss[tid] = ss[tid] * __expf(sm[tid] - Mn) + s2 * __expf(m2 - Mn);
            sm[tid] = Mn;
        }
        __syncthreads();
    }
    const float C = sm[0] + logf(ss[0]);
    for (int v = blockIdx.x * 256 + tid; v < V; v += gridDim.x * 256)
        logits[v] -= C;
}

extern "C" void kernel_launch(void* const* d_in, const int* in_sizes, int n_in,
                              void* d_out, int out_size, void* d_ws, size_t ws_size,
                              hipStream_t stream) {
    const int*   tok    = (const int*)d_in[0];
    const float* h0     = (const float*)d_in[1];
    const float* c0     = (const float*)d_in[2];
    const float* enc    = (const float*)d_in[3];
    const float* emb    = (const float*)d_in[4];
    const float* attn_W = (const float*)d_in[5];
    const float* attn_b = (const float*)d_in[6];
    const float* a2d_W  = (const float*)d_in[7];
    const float* a2d_b  = (const float*)d_in[8];
    const float* W_ih   = (const float*)d_in[9];
    const float* W_hh   = (const float*)d_in[10];
    const float* b_ih   = (const float*)d_in[11];
    const float* b_hh   = (const float*)d_in[12];
    const float* out_W  = (const float*)d_in[13];
    const float* out_b  = (const float*)d_in[14];

    float* out        = (float*)d_out;
    float* ws         = (float*)d_ws;
    float* out_logits = out;                 // V
    float* out_h      = out + V;             // H
    float* out_c      = out + V + H;         // H
    float* out_attnw  = out + V + 2 * H;     // L

    k_attn_logits<<<16, 256, 0, stream>>>(tok, h0, emb, attn_W, attn_b, ws);
    k_attn_out<<<4, 256, 0, stream>>>(enc, out_attnw, ws);
    k_a2d<<<256, 256, 0, stream>>>(a2d_W, a2d_b, ws);
    k_lstm<<<256, 256, 0, stream>>>(h0, c0, W_ih, W_hh, b_ih, b_hh, out_h, out_c, ws);
    k_vocab<<<NBLK5, 256, 0, stream>>>(out_W, out_b, out_logits, ws);
    k_final<<<256, 256, 0, stream>>>(out_logits, ws);
}

// Round 3
// 65.357 us; speedup vs baseline: 1.0957x; 1.0957x over previous
//
#include <hip/hip_runtime.h>
#include <math.h>

#define V 50257
#define H 1024
#define E 512
#define L 128
#define HE 1536            // H + E
#define NBLK5 2048         // blocks for vocab matvec -> 8192 waves
#define VSTRIDE (NBLK5 * 4)

// ws layout (floats)
#define WS_DECRAW 0        // 1536: [embed(512) | attn_out(1024)]
#define WS_DECIN  1536     // 1024: relu(a2d)
#define WS_HNEW   2560     // 1024: aligned copy of h_new
#define WS_ALOGIT 3584     // 128 : raw attention logits
#define WS_PAIRS  3712     // 2*NBLK5: (max, sumexp) per k_vocab block

typedef float f32x4 __attribute__((ext_vector_type(4)));

__device__ __forceinline__ float wave_reduce_sum(float v) {
    #pragma unroll
    for (int off = 32; off > 0; off >>= 1) v += __shfl_xor(v, off, 64);
    return v;
}

__device__ __forceinline__ float4 ntload(const float4* p) {
    f32x4 r = __builtin_nontemporal_load((const f32x4*)p);
    return make_float4(r.x, r.y, r.z, r.w);
}

// -------- K1a: attention logits. 128 blocks x 384 (block per row) --------
__global__ void k_attn_logits(const int* __restrict__ tok_p,
                              const float* __restrict__ h0,
                              const float* __restrict__ emb,
                              const float* __restrict__ attn_W,
                              const float* __restrict__ attn_b,
                              float* __restrict__ ws) {
    __shared__ __align__(16) float s_in[HE];
    __shared__ float s_part[6];
    const int tid = threadIdx.x;                 // 0..383
    const int tok = tok_p[0];
    for (int k = tid; k < HE; k += 384) {
        float v = (k < E) ? emb[(size_t)tok * E + k] : h0[k - E];
        s_in[k] = v;
        if (blockIdx.x == 0 && k < E) ws[WS_DECRAW + k] = v;
    }
    __syncthreads();
    const int lane = tid & 63, w = tid >> 6;     // w 0..5
    const int r = blockIdx.x;                    // 0..127
    const float4* s4 = (const float4*)s_in;
    const float4* w4 = (const float4*)(attn_W + (size_t)r * HE);
    float4 a = s4[lane + (w << 6)];
    float4 b = w4[lane + (w << 6)];
    float acc = a.x * b.x + a.y * b.y + a.z * b.z + a.w * b.w;
    acc = wave_reduce_sum(acc);
    if (lane == 0) s_part[w] = acc;
    __syncthreads();
    if (tid == 0) {
        float t = s_part[0] + s_part[1] + s_part[2] + s_part[3] + s_part[4] + s_part[5];
        ws[WS_ALOGIT + r] = t + attn_b[r];
    }
}

// -------- K1b: softmax + attn_out. 16 blocks x 256 (64 j's per block) -----
__global__ void k_attn_out(const float* __restrict__ enc,
                           float* __restrict__ out_attnw,
                           float* __restrict__ ws) {
    __shared__ float s_wn[L];
    __shared__ float s_acc[4][64];
    const int tid = threadIdx.x;
    if (tid < L) s_wn[tid] = ws[WS_ALOGIT + tid];
    __syncthreads();
    float m = -1e30f;
    #pragma unroll
    for (int l = 0; l < L; ++l) m = fmaxf(m, s_wn[l]);
    float s = 0.f;
    #pragma unroll
    for (int l = 0; l < L; ++l) s += __expf(s_wn[l] - m);
    __syncthreads();
    if (tid < L) {
        float wn = __expf(s_wn[tid] - m) / s;
        s_wn[tid] = wn;
        if (blockIdx.x == 0) out_attnw[tid] = wn;
    }
    __syncthreads();
    const int j = blockIdx.x * 64 + (tid & 63);
    const int lg = tid >> 6;                     // 0..3 -> l-range of 32
    float acc = 0.f;
    #pragma unroll
    for (int li = 0; li < 32; ++li) {
        const int l = (lg << 5) + li;
        acc = fmaf(s_wn[l], enc[l * H + j], acc);
    }
    s_acc[lg][tid & 63] = acc;
    __syncthreads();
    if (tid < 64) {
        float r = s_acc[0][tid] + s_acc[1][tid] + s_acc[2][tid] + s_acc[3][tid];
        ws[WS_DECRAW + E + blockIdx.x * 64 + tid] = r;
    }
}

// -------- K2: dec_in = relu(dec_in_raw @ a2d_W.T + b). 1024 blocks x 384 --
__global__ void k_a2d(const float* __restrict__ a2d_W,
                      const float* __restrict__ a2d_b,
                      float* __restrict__ ws) {
    __shared__ float s_part[6];
    const int tid = threadIdx.x, lane = tid & 63, w = tid >> 6;
    const int r = blockIdx.x;                    // 0..1023
    const float4* x4 = (const float4*)(ws + WS_DECRAW);
    const float4* w4 = (const float4*)(a2d_W + (size_t)r * HE);
    float4 a = x4[lane + (w << 6)];
    float4 b = w4[lane + (w << 6)];
    float acc = a.x * b.x + a.y * b.y + a.z * b.z + a.w * b.w;
    acc = wave_reduce_sum(acc);
    if (lane == 0) s_part[w] = acc;
    __syncthreads();
    if (tid == 0) {
        float t = s_part[0] + s_part[1] + s_part[2] + s_part[3] + s_part[4] + s_part[5];
        ws[WS_DECIN + r] = fmaxf(t + a2d_b[r], 0.f);
    }
}

// -------- K3: LSTM. 1024 blocks x 256, wave-per-gate, block-per-j ---------
__global__ void k_lstm(const float* __restrict__ h0,
                       const float* __restrict__ c0,
                       const float* __restrict__ W_ih,
                       const float* __restrict__ W_hh,
                       const float* __restrict__ b_ih,
                       const float* __restrict__ b_hh,
                       float* __restrict__ out_h,
                       float* __restrict__ out_c,
                       float* __restrict__ ws) {
    __shared__ float s_g[4];
    const int tid = threadIdx.x, lane = tid & 63, w = tid >> 6;   // w = gate
    const int j = blockIdx.x;                                     // 0..1023
    const float4* x4 = (const float4*)(ws + WS_DECIN);
    const float4* h4 = (const float4*)h0;
    const size_t r = (size_t)w * H + j;
    const float4* wi4 = (const float4*)(W_ih + r * H);
    const float4* wh4 = (const float4*)(W_hh + r * H);
    float acc = 0.f;
    #pragma unroll
    for (int k = 0; k < 4; ++k) {
        float4 a = ntload(wi4 + lane + (k << 6));
        float4 x = x4[lane + (k << 6)];
        acc = fmaf(a.x, x.x, acc); acc = fmaf(a.y, x.y, acc);
        acc = fmaf(a.z, x.z, acc); acc = fmaf(a.w, x.w, acc);
        float4 b = ntload(wh4 + lane + (k << 6));
        float4 h = h4[lane + (k << 6)];
        acc = fmaf(b.x, h.x, acc); acc = fmaf(b.y, h.y, acc);
        acc = fmaf(b.z, h.z, acc); acc = fmaf(b.w, h.w, acc);
    }
    acc = wave_reduce_sum(acc);
    if (lane == 0) s_g[w] = acc;
    __syncthreads();
    if (tid == 0) {
        float gi_ = s_g[0] + b_ih[j]         + b_hh[j];
        float gf  = s_g[1] + b_ih[H + j]     + b_hh[H + j];
        float gg  = s_g[2] + b_ih[2 * H + j] + b_hh[2 * H + j];
        float go  = s_g[3] + b_ih[3 * H + j] + b_hh[3 * H + j];
        float si = 1.f / (1.f + expf(-gi_));
        float sf = 1.f / (1.f + expf(-gf));
        float so = 1.f / (1.f + expf(-go));
        float cn = sf * c0[j] + si * tanhf(gg);
        float hn = so * tanhf(cn);
        out_c[j] = cn;
        out_h[j] = hn;
        ws[WS_HNEW + j] = hn;
    }
}

// -------- K5: vocab matvec, 2 rows in flight per wave ---------------------
__global__ void k_vocab(const float* __restrict__ out_W,
                        const float* __restrict__ out_b,
                        float* __restrict__ logits,
                        float* __restrict__ ws) {
    const int lane = threadIdx.x & 63;
    const int widx = threadIdx.x >> 6;
    const int gw = (blockIdx.x << 2) + widx;          // 0..8191
    const float4* h4 = (const float4*)(ws + WS_HNEW);
    float4 hr[4];
    #pragma unroll
    for (int k = 0; k < 4; ++k) hr[k] = h4[lane + (k << 6)];
    float m = -1e30f, s = 0.f;
    for (int v = gw; v < V; v += 2 * VSTRIDE) {
        const int v2 = v + VSTRIDE;
        const float4* w0 = (const float4*)(out_W + (size_t)v * H);
        float acc0 = 0.f, acc1 = 0.f;
        #pragma unroll
        for (int k = 0; k < 4; ++k) {
            float4 a = ntload(w0 + lane + (k << 6));
            acc0 = fmaf(hr[k].x, a.x, acc0); acc0 = fmaf(hr[k].y, a.y, acc0);
            acc0 = fmaf(hr[k].z, a.z, acc0); acc0 = fmaf(hr[k].w, a.w, acc0);
        }
        if (v2 < V) {
            const float4* w1 = (const float4*)(out_W + (size_t)v2 * H);
            #pragma unroll
            for (int k = 0; k < 4; ++k) {
                float4 a = ntload(w1 + lane + (k << 6));
                acc1 = fmaf(hr[k].x, a.x, acc1); acc1 = fmaf(hr[k].y, a.y, acc1);
                acc1 = fmaf(hr[k].z, a.z, acc1); acc1 = fmaf(hr[k].w, a.w, acc1);
            }
        }
        acc0 = wave_reduce_sum(acc0);
        float l0 = acc0 + out_b[v];
        if (lane == 0) logits[v] = l0;
        float mo = m;
        m = fmaxf(m, l0);
        s = s * __expf(mo - m) + __expf(l0 - m);
        if (v2 < V) {
            acc1 = wave_reduce_sum(acc1);
            float l1 = acc1 + out_b[v2];
            if (lane == 0) logits[v2] = l1;
            mo = m;
            m = fmaxf(m, l1);
            s = s * __expf(mo - m) + __expf(l1 - m);
        }
    }
    __shared__ float sm[4], ss[4];
    if (lane == 0) { sm[widx] = m; ss[widx] = s; }
    __syncthreads();
    if (threadIdx.x == 0) {
        float M = sm[0], S = ss[0];
        #pragma unroll
        for (int i = 1; i < 4; ++i) {
            float Mn = fmaxf(M, sm[i]);
            S = S * __expf(M - Mn) + ss[i] * __expf(sm[i] - Mn);
            M = Mn;
        }
        ws[WS_PAIRS + 2 * blockIdx.x]     = M;
        ws[WS_PAIRS + 2 * blockIdx.x + 1] = S;
    }
}

// -------- K6: fold partials + finalize log-softmax ------------------------
__global__ void k_final(float* __restrict__ logits,
                        const float* __restrict__ ws) {
    __shared__ float sm[256], ss[256];
    const int tid = threadIdx.x;
    float M = -1e30f, S = 0.f;
    for (int i = tid; i < NBLK5; i += 256) {
        float m2 = ws[WS_PAIRS + 2 * i], s2 = ws[WS_PAIRS + 2 * i + 1];
        float Mn = fmaxf(M, m2);
        S = S * __expf(M - Mn) + s2 * __expf(m2 - Mn);
        M = Mn;
    }
    sm[tid] = M; ss[tid] = S;
    __syncthreads();
    for (int off = 128; off > 0; off >>= 1) {
        if (tid < off) {
            float m2 = sm[tid + off], s2 = ss[tid + off];
            float Mn = fmaxf(sm[tid], m2);
            ss[tid] = ss[tid] * __expf(sm[tid] - Mn) + s2 * __expf(m2 - Mn);
            sm[tid] = Mn;
        }
        __syncthreads();
    }
    const float C = sm[0] + logf(ss[0]);
    for (int v = blockIdx.x * 256 + tid; v < V; v += gridDim.x * 256)
        logits[v] -= C;
}

extern "C" void kernel_launch(void* const* d_in, const int* in_sizes, int n_in,
                              void* d_out, int out_size, void* d_ws, size_t ws_size,
                              hipStream_t stream) {
    const int*   tok    = (const int*)d_in[0];
    const float* h0     = (const float*)d_in[1];
    const float* c0     = (const float*)d_in[2];
    const float* enc    = (const float*)d_in[3];
    const float* emb    = (const float*)d_in[4];
    const float* attn_W = (const float*)d_in[5];
    const float* attn_b = (const float*)d_in[6];
    const float* a2d_W  = (const float*)d_in[7];
    const float* a2d_b  = (const float*)d_in[8];
    const float* W_ih   = (const float*)d_in[9];
    const float* W_hh   = (const float*)d_in[10];
    const float* b_ih   = (const float*)d_in[11];
    const float* b_hh   = (const float*)d_in[12];
    const float* out_W  = (const float*)d_in[13];
    const float* out_b  = (const float*)d_in[14];

    float* out        = (float*)d_out;
    float* ws         = (float*)d_ws;
    float* out_logits = out;                 // V
    float* out_h      = out + V;             // H
    float* out_c      = out + V + H;         // H
    float* out_attnw  = out + V + 2 * H;     // L

    k_attn_logits<<<128, 384, 0, stream>>>(tok, h0, emb, attn_W, attn_b, ws);
    k_attn_out<<<16, 256, 0, stream>>>(enc, out_attnw, ws);
    k_a2d<<<1024, 384, 0, stream>>>(a2d_W, a2d_b, ws);
    k_lstm<<<1024, 256, 0, stream>>>(h0, c0, W_ih, W_hh, b_ih, b_hh, out_h, out_c, ws);
    k_vocab<<<NBLK5, 256, 0, stream>>>(out_W, out_b, out_logits, ws);
    k_final<<<256, 256, 0, stream>>>(out_logits, ws);
}